// Round 17
// baseline (967.348 us; speedup 1.0000x reference)
//
#include <hip/hip_runtime.h>
#include <math.h>

#define NN 4096
#define QQ 1024
#define LDA 1032              // padded leading dim (16B-aligned rows)
#define AF (1025 * 1032)      // floats occupied by bordered matrix A (1025 rows)

// scal layout: [0]=rr, [2]=w-chunk-sq accumulator (atomic), [16..143]=st partials

// ======== rank-2 register potrf of a 64x64 tile (256 threads) ========
__device__ __forceinline__ void potrf64_run(float (&x)[16], int i, int q,
                                            float2 (&col2)[2][64]) {
#pragma unroll
    for (int qk = 0; qk < 4; ++qk) {
#pragma unroll
        for (int c2 = 0; c2 < 8; ++c2) {
            const int k = qk * 16 + 2 * c2;
            const int ck = 2 * c2;
            const int b = c2 & 1;
            if (q == qk) {                        // wave-uniform
                float xk = x[ck];
                float d0 = __shfl(xk, k, 64);
                float rs0 = rsqrtf(d0);
                float l0 = (i == k) ? d0 * rs0 : xk * rs0;
                if (i >= k) x[ck] = l0;
                float lk1 = __shfl(l0, k + 1, 64);
                float x1v = fmaf(-l0, lk1, x[ck + 1]);
                float d1 = __shfl(x1v, k + 1, 64);
                float rs1 = rsqrtf(d1);
                float l1 = (i == k + 1) ? d1 * rs1 : x1v * rs1;
                if (i >= k + 1) x[ck + 1] = l1;
                col2[b][i] = make_float2(l0, l1);
            }
            __syncthreads();
            if (16 * q + 15 > k + 1 && i > k) {
                float2 lp = col2[b][i];
                const float4* cp = (const float4*)(&col2[b][16 * q]);
#pragma unroll
                for (int m2 = 0; m2 < 8; ++m2) {
                    float4 v = cp[m2];
                    if (16 * q + 2 * m2 > k + 1)
                        x[2 * m2] = fmaf(-lp.x, v.x, fmaf(-lp.y, v.y, x[2 * m2]));
                    if (16 * q + 2 * m2 + 1 > k + 1)
                        x[2 * m2 + 1] = fmaf(-lp.x, v.z, fmaf(-lp.y, v.w, x[2 * m2 + 1]));
                }
            }
        }
    }
}

// ======== zero-barrier column-major trsm: X * L^T = T (64x64, LDS ld=68) ====
// Row-independent forward substitution (R15-verified): lane c of wave q owns
// X[16q+m][c]; step k broadcasts lane k's column via in-wave __shfl; the
// Lb[c][k] read is off the dependency chain. No __syncthreads in the sweep.
template<bool DUAL>
__device__ __forceinline__ void trsm64_cols(float* Tr, float* Tc,
                                            const float (&Lb)[64][65],
                                            const float (&dinv)[64]) {
    const int tid = threadIdx.x;
    const int c = tid & 63, q = tid >> 6;
    float xr[16], xc[16];
#pragma unroll
    for (int m = 0; m < 16; ++m) {
        xr[m] = Tr[(16 * q + m) * 68 + c];
        if (DUAL) xc[m] = Tc[(16 * q + m) * 68 + c];
    }
    const float dv = dinv[c];
#pragma unroll
    for (int k = 0; k < 64; ++k) {
        if (c == k) {
#pragma unroll
            for (int m = 0; m < 16; ++m) {
                xr[m] *= dv;
                if (DUAL) xc[m] *= dv;
            }
        }
        float lck = Lb[c][k];          // off-chain, conflict-free
#pragma unroll
        for (int m = 0; m < 16; ++m) {
            float a = __shfl(xr[m], k, 64);
            if (c > k) xr[m] = fmaf(-a, lck, xr[m]);
            if (DUAL) {
                float bb = __shfl(xc[m], k, 64);
                if (c > k) xc[m] = fmaf(-bb, lck, xc[m]);
            }
        }
    }
#pragma unroll
    for (int m = 0; m < 16; ++m) {
        Tr[(16 * q + m) * 68 + c] = xr[m];
        if (DUAL) Tc[(16 * q + m) * 68 + c] = xc[m];
    }
    __syncthreads();   // solved tiles visible before syrk reads
}

// acc += U·V^T  (register accumulator, 4x4 per thread)
__device__ __forceinline__ void acc_syrk(float (&acc)[4][4], const float* U,
                                         const float* V) {
    int tx = threadIdx.x & 15, ty = threadIdx.x >> 4;
    float4 ar4[4], br4[4];
#pragma unroll 4
    for (int k4 = 0; k4 < 16; ++k4) {
#pragma unroll
        for (int ii = 0; ii < 4; ++ii)
            ar4[ii] = *(const float4*)(U + (ty + 16 * ii) * 68 + 4 * k4);
#pragma unroll
        for (int jj = 0; jj < 4; ++jj)
            br4[jj] = *(const float4*)(V + (tx + 16 * jj) * 68 + 4 * k4);
#pragma unroll
        for (int ii = 0; ii < 4; ++ii)
#pragma unroll
            for (int jj = 0; jj < 4; ++jj) {
                acc[ii][jj] = fmaf(ar4[ii].x, br4[jj].x, acc[ii][jj]);
                acc[ii][jj] = fmaf(ar4[ii].y, br4[jj].y, acc[ii][jj]);
                acc[ii][jj] = fmaf(ar4[ii].z, br4[jj].z, acc[ii][jj]);
                acc[ii][jj] = fmaf(ar4[ii].w, br4[jj].w, acc[ii][jj]);
            }
    }
}

// ======== panel tile: register-first staging + trsm + syrk + diag potrf ====
// R16 change: the cold stage IS the critical path (R14's 2x-staging pair ran
// 2.7x one panel; 3 trsm variants changed nothing). Issue ALL 12 float4
// global loads (Pr, Pc, Lb-vectorized) + dinv scalar back-to-back into
// registers — one batch of concurrent HBM fetches — then drain to LDS.
__device__ __forceinline__ void panel_tile(
    float* __restrict__ A, float* __restrict__ scal, int p, int by, int bx,
    int nr, int ncol, float (&PrRaw)[64 * 68], float (&PcRaw)[64 * 68],
    float2 (&col2)[2][64], float (&Lb)[64][65], float (&dinv)[64]) {
    const int tid = threadIdx.x;
    const int lane = tid & 63, wid = tid >> 6;
    int t0v = (p + 1) * 64;
    int r0 = t0v + by * 64;
    int c0 = t0v + bx * 64;
    bool wrow = (by == nr - 1);           // tile row = row QQ only
    bool same_rc = (bx == by) && !wrow;   // diag tile (incl. dfuse)
    bool dfuse = (bx == 0 && by == 0);
    int pc0 = p * 64;
    const float* db = A + (size_t)pc0 * (LDA + 1);

    // ---- issue ALL stage loads first (max outstanding), then LDS writes ----
    float4 vr[4], vc[4], vl[4];
    float dval = 0.f;
    if (tid < 64) dval = db[(size_t)tid * (LDA + 1)];
#pragma unroll
    for (int it = 0; it < 4; ++it) {
        int idx2 = tid + 256 * it;          // 0..1023
        int rr = idx2 >> 4, c4 = idx2 & 15;
        int gr = r0 + rr;
        vr[it] = (gr <= QQ) ? *(const float4*)(A + (size_t)gr * LDA + pc0 + 4 * c4)
                            : make_float4(0.f, 0.f, 0.f, 0.f);
        if (!same_rc)
            vc[it] = *(const float4*)(A + (size_t)(c0 + rr) * LDA + pc0 + 4 * c4);
        vl[it] = *(const float4*)(db + (size_t)rr * LDA + 4 * c4);   // Lb row rr
    }
#pragma unroll
    for (int it = 0; it < 4; ++it) {
        int idx2 = tid + 256 * it;
        int rr = idx2 >> 4, c4 = idx2 & 15;
        *(float4*)(PrRaw + rr * 68 + 4 * c4) = vr[it];
        if (!same_rc) *(float4*)(PcRaw + rr * 68 + 4 * c4) = vc[it];
        Lb[rr][4 * c4]     = vl[it].x;
        Lb[rr][4 * c4 + 1] = vl[it].y;
        Lb[rr][4 * c4 + 2] = vl[it].z;
        Lb[rr][4 * c4 + 3] = vl[it].w;
    }
    if (tid < 64) dinv[tid] = 1.0f / dval;
    __syncthreads();

    // zero-barrier trsm (wrow Pr rows 1..63 are staged zeros -> no-op rows)
    if (same_rc) trsm64_cols<false>(PrRaw, PcRaw, Lb, dinv);
    else         trsm64_cols<true >(PrRaw, PcRaw, Lb, dinv);
    if (wrow && bx == 0 && wid == 0) {    // sum(solved w-chunk^2), row 0 of Pr
        float xv = PrRaw[lane];
        float v = xv * xv;
        for (int o = 32; o > 0; o >>= 1) v += __shfl_down(v, o, 64);
        if (lane == 0) atomicAdd(&scal[2], v);
    }
    // syrk from trsm'd LDS tiles
    const float* PB = same_rc ? PrRaw : PcRaw;
    int tx = tid & 15, ty = tid >> 4;
    // dfuse: preload raw next-diag values BEFORE syrk so latency hides under it
    float oldv[4][4];
    if (dfuse) {
#pragma unroll
        for (int ii = 0; ii < 4; ++ii)
#pragma unroll
            for (int jj = 0; jj < 4; ++jj)
                oldv[ii][jj] = A[(size_t)(r0 + ty + 16 * ii) * LDA + c0 + tx + 16 * jj];
    }
    float acc[4][4];
#pragma unroll
    for (int ii = 0; ii < 4; ++ii)
#pragma unroll
        for (int jj = 0; jj < 4; ++jj) acc[ii][jj] = 0.f;
    acc_syrk(acc, PrRaw, PB);
    if (!dfuse) {
#pragma unroll
        for (int ii = 0; ii < 4; ++ii) {
            int rr = r0 + ty + 16 * ii;
            if (rr <= QQ) {
#pragma unroll
                for (int jj = 0; jj < 4; ++jj)
                    A[(size_t)rr * LDA + c0 + tx + 16 * jj] -= acc[ii][jj];
            }
        }
    } else {
        // updated next diag tile -> LDS (stride-65 view of PcRaw), then factor
#pragma unroll
        for (int ii = 0; ii < 4; ++ii) {
            int lr = ty + 16 * ii;
#pragma unroll
            for (int jj = 0; jj < 4; ++jj)
                PcRaw[lr * 65 + tx + 16 * jj] = oldv[ii][jj] - acc[ii][jj];
        }
        __syncthreads();
        int i = tid & 63, q = tid >> 6;
        float x[16];
#pragma unroll
        for (int m = 0; m < 16; ++m) x[m] = PcRaw[i * 65 + 16 * q + m];
        potrf64_run(x, i, q, col2);
        float* row = A + (size_t)(r0 + i) * LDA + c0 + 16 * q;
#pragma unroll
        for (int m4 = 0; m4 < 4; ++m4)
            ((float4*)row)[m4] = make_float4(x[4 * m4], x[4 * m4 + 1],
                                             x[4 * m4 + 2], x[4 * m4 + 3]);
    }
}

// ======== k_front: 256 blocks — stats/matvec/build/potrf0 (R7-verified) ========
__global__ __launch_bounds__(256) void k_front(
    const float* __restrict__ yt, const float* __restrict__ yp,
    const int* __restrict__ idx, const float* __restrict__ dist,
    const float* __restrict__ se_p, const float* __restrict__ sbs,
    float* __restrict__ A, float* __restrict__ scal) {
    const int bid = blockIdx.x, tid = threadIdx.x;
    const int lane = tid & 63, wid = tid >> 6;
    __shared__ int   c_l[1024];
    __shared__ float s_l[1024];
    __shared__ float sq_l[1024];
    __shared__ __align__(16) float Pc[64 * 65];
    __shared__ float2 col2[2][64];
    __shared__ float red[4];
    float sb0 = sbs[0];
    float inv2 = 1.0f / (2.0f * sbs[1]);
    float inv_se = 1.0f / se_p[0];
    bool mv = (bid >= 128);

    for (int j = tid; j < 1024; j += 256) { c_l[j] = 0; s_l[j] = 0.f; }
    __syncthreads();
    float rr_acc = 0.f;
#pragma unroll
    for (int e4 = 0; e4 < 16; ++e4) {      // compile-time trip: loads batched
        int e = tid + 256 * e4;
        int q = idx[e];
        atomicAdd(&c_l[q], 1);
        if (mv) {
            float r = yt[e] - yp[e];
            atomicAdd(&s_l[q], r);
            rr_acc += r * r;
        }
    }
    __syncthreads();
    for (int j = tid; j < 1024; j += 256) sq_l[j] = sqrtf((float)c_l[j]);
    __syncthreads();

    if (bid == 0) {
        // build 64x64 diag tile in LDS, factor, write cols 0..63 only
        for (int kk = tid; kk < 4096; kk += 256) {
            int i = kk >> 6, j = kk & 63;
            float qi = sq_l[i] * inv_se * sb0;
            Pc[i * 65 + j] = ((i == j) ? 1.0f : 0.0f)
                           + qi * sq_l[j] * __expf(-dist[(size_t)i * QQ + j] * inv2);
        }
        __syncthreads();
        int i = lane, q = wid;
        float x[16];
#pragma unroll
        for (int m = 0; m < 16; ++m) x[m] = Pc[i * 65 + 16 * q + m];
        potrf64_run(x, i, q, col2);
        float* row = A + (size_t)i * LDA + 16 * q;
#pragma unroll
        for (int m4 = 0; m4 < 4; ++m4)
            ((float4*)row)[m4] = make_float4(x[4 * m4], x[4 * m4 + 1],
                                             x[4 * m4 + 2], x[4 * m4 + 3]);
        if (tid == 0) scal[2] = 0.f;    // w-chunk sq accumulator (panels add)
    } else if (!mv) {
        // blocks 1..127: rows 64..1023, one float4/thread/row
        for (int i = 64 + (bid - 1); i < QQ; i += 127) {
            float qi = sq_l[i] * inv_se * sb0;
            float4 d = ((const float4*)(dist + (size_t)i * QQ))[tid];
            int j0 = 4 * tid;
            float4 o;
            o.x = ((i == j0    ) ? 1.0f : 0.0f) + qi * sq_l[j0    ] * __expf(-d.x * inv2);
            o.y = ((i == j0 + 1) ? 1.0f : 0.0f) + qi * sq_l[j0 + 1] * __expf(-d.y * inv2);
            o.z = ((i == j0 + 2) ? 1.0f : 0.0f) + qi * sq_l[j0 + 2] * __expf(-d.z * inv2);
            o.w = ((i == j0 + 3) ? 1.0f : 0.0f) + qi * sq_l[j0 + 3] * __expf(-d.w * inv2);
            ((float4*)(A + (size_t)i * LDA))[tid] = o;
        }
    } else {
        int m = bid - 128;
        if (bid == 128) {   // rr reduce -> scal[0]
            float v = rr_acc;
            for (int o = 32; o > 0; o >>= 1) v += __shfl_down(v, o, 64);
            if (lane == 0) red[wid] = v;
            __syncthreads();
            if (tid == 0) scal[0] = red[0] + red[1] + red[2] + red[3];
            __syncthreads();
        }
        // 8 matvec rows: 2 per wave; inner dot fully unrolled (16 loads in flight)
        float st_acc = 0.f;
#pragma unroll
        for (int h = 0; h < 2; ++h) {
            int row = m * 8 + wid * 2 + h;
            const float* dr = dist + (size_t)row * QQ;
            float acc = 0.f;
#pragma unroll
            for (int j4 = 0; j4 < 16; ++j4) {
                int j = lane + 64 * j4;
                acc += __expf(-dr[j] * inv2) * s_l[j];
            }
            for (int o = 32; o > 0; o >>= 1) acc += __shfl_down(acc, o, 64);
            if (lane == 0) {
                float tv = acc * sb0;
                A[(size_t)QQ * LDA + row] = sq_l[row] * tv;   // w-row
                st_acc += s_l[row] * tv;
            }
        }
        __syncthreads();
        if (lane == 0) red[wid] = st_acc;
        __syncthreads();
        if (tid == 0) scal[16 + m] = red[0] + red[1] + red[2] + red[3];
    }
}

// ======== k_panel: one tile per block (p = 0..14) ========
__global__ __launch_bounds__(256) void k_panel(float* __restrict__ A,
                                               float* __restrict__ scal, int p) {
    __shared__ __align__(16) float PrRaw[64 * 68];
    __shared__ __align__(16) float PcRaw[64 * 68];
    __shared__ float2 col2[2][64];
    __shared__ float Lb[64][65];
    __shared__ float dinv[64];
    int t0v = (p + 1) * 64;
    int rows = (QQ + 1) - t0v;
    int nr = (rows + 63) >> 6;
    int ncol = (QQ - t0v) / 64;
    int by = -1, bx = 0, rem = blockIdx.x;
    for (int b = 0; b < nr; ++b) {
        int cn = (b + 1 < ncol) ? (b + 1) : ncol;
        if (cn < 1) cn = 1;                // p=14: ncol=0, but w-row tile exists
        if (rem < cn) { by = b; bx = rem; break; }
        rem -= cn;
    }
    if (by < 0) return;
    panel_tile(A, scal, p, by, bx, nr, ncol, PrRaw, PcRaw, col2, Lb, dinv);
}

// ======== k_final: solve chunk 15 vs factored diag15, reduce, combine ========
__global__ __launch_bounds__(256) void k_final(float* __restrict__ A,
                                               float* __restrict__ scal,
                                               const float* __restrict__ se_p,
                                               float* __restrict__ out) {
    const int tid = threadIdx.x;
    const int lane = tid & 63, wid = tid >> 6;
    __shared__ float Lb[64][65];
    __shared__ float r1s[4], r2s[4], r3s[4];
    __shared__ float wl[64];
    const float* db15 = A + (size_t)960 * LDA + 960;
    for (int kk = tid; kk < 4096; kk += 256) {
        int ii = kk >> 6, jj = kk & 63;
        Lb[ii][jj] = db15[(size_t)ii * LDA + jj];
    }
    __syncthreads();
    if (tid < 64) {
        float xv = A[(size_t)QQ * LDA + 960 + tid];
        for (int k = 0; k < 64; ++k) {
            if (tid == k) xv /= Lb[k][k];
            float xk = __shfl(xv, k, 64);
            if (tid > k) xv = fmaf(-Lb[tid][k], xk, xv);
        }
        wl[tid] = xv;
    }
    __syncthreads();
    float v1 = 0.f, v2 = 0.f;
    for (int i = tid; i < QQ; i += 256) {
        v1 += __logf(A[(size_t)i * LDA + i]);
        if (i >= 960) { float yv = wl[i - 960]; v2 += yv * yv; }
    }
    v1 *= 2.0f;
    float v3 = (tid < 128) ? scal[16 + tid] : 0.f;   // st partials
    for (int o = 32; o > 0; o >>= 1) {
        v1 += __shfl_down(v1, o, 64);
        v2 += __shfl_down(v2, o, 64);
        v3 += __shfl_down(v3, o, 64);
    }
    if (lane == 0) { r1s[wid] = v1; r2s[wid] = v2; r3s[wid] = v3; }
    __syncthreads();
    if (tid == 0) {
        float ld = r1s[0] + r1s[1] + r1s[2] + r1s[3];
        float wsq = __hip_atomic_load(&scal[2], __ATOMIC_RELAXED, __HIP_MEMORY_SCOPE_AGENT);
        float yy = r2s[0] + r2s[1] + r2s[2] + r2s[3] + wsq;  // chunks 0..14 + 15
        float st = r3s[0] + r3s[1] + r3s[2] + r3s[3];
        float se = se_p[0], inv = 1.0f / se;
        float rr = scal[0];
        float quad = rr * inv - inv * inv * (st - inv * yy);
        float logdetV = (float)NN * __logf(se) + ld;
        out[0] = 0.5f * (float)NN * 1.8378770664093453f + 0.5f * logdetV + 0.5f * quad;
    }
}

extern "C" void kernel_launch(void* const* d_in, const int* in_sizes, int n_in,
                              void* d_out, int out_size, void* d_ws, size_t ws_size,
                              hipStream_t stream) {
    const float* yt   = (const float*)d_in[0];
    const float* yp   = (const float*)d_in[1];
    const int*   idx  = (const int*)d_in[2];
    const float* dist = (const float*)d_in[3];
    const float* se   = (const float*)d_in[4];
    const float* sbs  = (const float*)d_in[5];
    float* out = (float*)d_out;

    float* W    = (float*)d_ws;
    float* A    = W;                      // 1025 x LDA
    float* scal = W + AF;                 // [0]=rr, [2]=wsq, [16..143]=st partials

    k_front<<<dim3(256), dim3(256), 0, stream>>>(yt, yp, idx, dist, se, sbs, A, scal);
    for (int p = 0; p <= 14; ++p) {
        int t0v = (p + 1) * 64;
        int nr = ((QQ + 1) - t0v + 63) / 64;
        int ncol = (QQ - t0v) / 64;
        int tiles = 0;
        for (int b = 0; b < nr; ++b) {
            int cn = (b + 1 < ncol) ? (b + 1) : ncol;
            if (cn < 1) cn = 1;           // p=14: w-row tile at ncol=0
            tiles += cn;
        }
        k_panel<<<dim3(tiles), dim3(256), 0, stream>>>(A, scal, p);
    }
    k_final<<<dim3(1), dim3(256), 0, stream>>>(A, scal, se, out);
}

// Round 18
// 642.582 us; speedup vs baseline: 1.5054x; 1.5054x over previous
//
#include <hip/hip_runtime.h>
#include <math.h>

#define NN 4096
#define QQ 1024
#define LDA 1032              // padded leading dim (16B-aligned rows)
#define AF (1025 * 1032)      // floats occupied by bordered matrix A (1025 rows)

// scal layout: [0]=rr, [2]=w-chunk-sq accumulator (atomic), [16..143]=st partials

// ======== rank-2 register potrf of a 64x64 tile (256 threads) ========
__device__ __forceinline__ void potrf64_run(float (&x)[16], int i, int q,
                                            float2 (&col2)[2][64]) {
#pragma unroll
    for (int qk = 0; qk < 4; ++qk) {
#pragma unroll
        for (int c2 = 0; c2 < 8; ++c2) {
            const int k = qk * 16 + 2 * c2;
            const int ck = 2 * c2;
            const int b = c2 & 1;
            if (q == qk) {                        // wave-uniform
                float xk = x[ck];
                float d0 = __shfl(xk, k, 64);
                float rs0 = rsqrtf(d0);
                float l0 = (i == k) ? d0 * rs0 : xk * rs0;
                if (i >= k) x[ck] = l0;
                float lk1 = __shfl(l0, k + 1, 64);
                float x1v = fmaf(-l0, lk1, x[ck + 1]);
                float d1 = __shfl(x1v, k + 1, 64);
                float rs1 = rsqrtf(d1);
                float l1 = (i == k + 1) ? d1 * rs1 : x1v * rs1;
                if (i >= k + 1) x[ck + 1] = l1;
                col2[b][i] = make_float2(l0, l1);
            }
            __syncthreads();
            if (16 * q + 15 > k + 1 && i > k) {
                float2 lp = col2[b][i];
                const float4* cp = (const float4*)(&col2[b][16 * q]);
#pragma unroll
                for (int m2 = 0; m2 < 8; ++m2) {
                    float4 v = cp[m2];
                    if (16 * q + 2 * m2 > k + 1)
                        x[2 * m2] = fmaf(-lp.x, v.x, fmaf(-lp.y, v.y, x[2 * m2]));
                    if (16 * q + 2 * m2 + 1 > k + 1)
                        x[2 * m2 + 1] = fmaf(-lp.x, v.z, fmaf(-lp.y, v.w, x[2 * m2 + 1]));
                }
            }
        }
    }
}

// ======== template-unrolled trsm helpers ========
template<int K, int M>
struct TAcc {
    static __device__ __forceinline__ void run(const float (&Lb)[64][65], const float (&x)[64],
                                               float& a0, float& a1) {
        if constexpr (M < K)     a0 = fmaf(-Lb[K][M], x[M], a0);
        if constexpr (M + 1 < K) a1 = fmaf(-Lb[K][M + 1], x[M + 1], a1);
        if constexpr (M + 2 < K) TAcc<K, M + 2>::run(Lb, x, a0, a1);
    }
};
template<int K>
struct TStep {
    static __device__ __forceinline__ void run(const float (&Lb)[64][65], const float (&dinv)[64],
                                               float (&x)[64]) {
        if constexpr (K < 64) {
            float a0 = x[K], a1 = 0.f;
            TAcc<K, 0>::run(Lb, x, a0, a1);
            x[K] = (a0 + a1) * dinv[K];
            TStep<K + 1>::run(Lb, dinv, x);
        }
    }
};

// ======== panel tile: fused trsm-in-LDS + syrk + next-diag potrf ========
__device__ __forceinline__ void panel_tile(
    float* __restrict__ A, float* __restrict__ scal, int p, int by, int bx,
    int nr, int ncol, float (&PrRaw)[64 * 68], float (&PcRaw)[64 * 68],
    float2 (&col2)[2][64], float (&Lb)[64][65], float (&dinv)[64]) {
    const int tid = threadIdx.x;
    const int lane = tid & 63, wid = tid >> 6;
    int t0v = (p + 1) * 64;
    int r0 = t0v + by * 64;
    int c0 = t0v + bx * 64;
    bool wrow = (by == nr - 1);           // tile row = row QQ only
    bool same_rc = (bx == by) && !wrow;   // diag tile (incl. dfuse)
    bool dfuse = (bx == 0 && by == 0);
    int pc0 = p * 64;
    const float* db = A + (size_t)pc0 * (LDA + 1);
    // stage raw panel tiles + Lb + dinv
    for (int idx2 = tid; idx2 < 1024; idx2 += 256) {
        int rr = idx2 >> 4, c4 = idx2 & 15;
        int gr = r0 + rr;
        float4 v = make_float4(0.f, 0.f, 0.f, 0.f);
        if (gr <= QQ) v = *(const float4*)(A + (size_t)gr * LDA + pc0 + 4 * c4);
        *(float4*)(PrRaw + rr * 68 + 4 * c4) = v;
        if (!same_rc) {
            float4 u = *(const float4*)(A + (size_t)(c0 + rr) * LDA + pc0 + 4 * c4);
            *(float4*)(PcRaw + rr * 68 + 4 * c4) = u;
        }
    }
    for (int kk = tid; kk < 4096; kk += 256) {
        int ii = kk >> 6, jj = kk & 63;
        Lb[ii][jj] = db[(size_t)ii * LDA + jj];
    }
    if (tid < 64) dinv[tid] = 1.0f / db[(size_t)tid * (LDA + 1)];
    __syncthreads();
    // trsm in LDS: wave 0 -> PrRaw rows, wave 1 -> PcRaw rows
    if (wid == 0 && wrow) {
        float xv = PrRaw[lane];
        for (int k = 0; k < 64; ++k) {
            if (lane == k) xv *= dinv[k];
            float xk = __shfl(xv, k, 64);
            if (lane > k) xv = fmaf(-Lb[lane][k], xk, xv);
        }
        PrRaw[lane] = xv;
        if (bx == 0) {
            float v = xv * xv;
            for (int o = 32; o > 0; o >>= 1) v += __shfl_down(v, o, 64);
            if (lane == 0) atomicAdd(&scal[2], v);
        }
    } else {
        float* tp = nullptr;
        if (wid == 0) tp = PrRaw + lane * 68;               // !wrow here
        else if (wid == 1 && !same_rc) tp = PcRaw + lane * 68;
        if (tp) {
            float x[64];
#pragma unroll
            for (int m = 0; m < 64; ++m) x[m] = tp[m];
            TStep<0>::run(Lb, dinv, x);
#pragma unroll
            for (int m = 0; m < 64; ++m) tp[m] = x[m];
        }
    }
    __syncthreads();
    // syrk from trsm'd LDS tiles
    const float* PB = same_rc ? PrRaw : PcRaw;
    int tx = tid & 15, ty = tid >> 4;
    float acc[4][4];
#pragma unroll
    for (int ii = 0; ii < 4; ++ii)
#pragma unroll
        for (int jj = 0; jj < 4; ++jj) acc[ii][jj] = 0.f;
    float4 ar4[4], br4[4];
#pragma unroll 4
    for (int k4 = 0; k4 < 16; ++k4) {
#pragma unroll
        for (int ii = 0; ii < 4; ++ii)
            ar4[ii] = *(const float4*)(PrRaw + (ty + 16 * ii) * 68 + 4 * k4);
#pragma unroll
        for (int jj = 0; jj < 4; ++jj)
            br4[jj] = *(const float4*)(PB + (tx + 16 * jj) * 68 + 4 * k4);
#pragma unroll
        for (int ii = 0; ii < 4; ++ii)
#pragma unroll
            for (int jj = 0; jj < 4; ++jj) {
                acc[ii][jj] = fmaf(ar4[ii].x, br4[jj].x, acc[ii][jj]);
                acc[ii][jj] = fmaf(ar4[ii].y, br4[jj].y, acc[ii][jj]);
                acc[ii][jj] = fmaf(ar4[ii].z, br4[jj].z, acc[ii][jj]);
                acc[ii][jj] = fmaf(ar4[ii].w, br4[jj].w, acc[ii][jj]);
            }
    }
    if (!dfuse) {
#pragma unroll
        for (int ii = 0; ii < 4; ++ii) {
            int rr = r0 + ty + 16 * ii;
            if (rr <= QQ) {
#pragma unroll
                for (int jj = 0; jj < 4; ++jj) {
                    float* pa = A + (size_t)rr * LDA + c0 + tx + 16 * jj;
                    *pa -= acc[ii][jj];
                }
            }
        }
    } else {
        // updated next diag tile -> LDS (stride-65 view of PcRaw), then factor
#pragma unroll
        for (int ii = 0; ii < 4; ++ii) {
            int lr = ty + 16 * ii;
#pragma unroll
            for (int jj = 0; jj < 4; ++jj) {
                int lc = tx + 16 * jj;
                float old = A[(size_t)(r0 + lr) * LDA + c0 + lc];
                PcRaw[lr * 65 + lc] = old - acc[ii][jj];
            }
        }
        __syncthreads();
        int i = tid & 63, q = tid >> 6;
        float x[16];
#pragma unroll
        for (int m = 0; m < 16; ++m) x[m] = PcRaw[i * 65 + 16 * q + m];
        potrf64_run(x, i, q, col2);
        float* row = A + (size_t)(r0 + i) * LDA + c0 + 16 * q;
#pragma unroll
        for (int m4 = 0; m4 < 4; ++m4)
            ((float4*)row)[m4] = make_float4(x[4 * m4], x[4 * m4 + 1],
                                             x[4 * m4 + 2], x[4 * m4 + 3]);
    }
}

// ======== k_front: 256 blocks — stats/matvec/build/potrf0 (R7-verified) ========
__global__ __launch_bounds__(256) void k_front(
    const float* __restrict__ yt, const float* __restrict__ yp,
    const int* __restrict__ idx, const float* __restrict__ dist,
    const float* __restrict__ se_p, const float* __restrict__ sbs,
    float* __restrict__ A, float* __restrict__ scal) {
    const int bid = blockIdx.x, tid = threadIdx.x;
    const int lane = tid & 63, wid = tid >> 6;
    __shared__ int   c_l[1024];
    __shared__ float s_l[1024];
    __shared__ float sq_l[1024];
    __shared__ __align__(16) float Pc[64 * 65];
    __shared__ float2 col2[2][64];
    __shared__ float red[4];
    float sb0 = sbs[0];
    float inv2 = 1.0f / (2.0f * sbs[1]);
    float inv_se = 1.0f / se_p[0];
    bool mv = (bid >= 128);

    for (int j = tid; j < 1024; j += 256) { c_l[j] = 0; s_l[j] = 0.f; }
    __syncthreads();
    float rr_acc = 0.f;
#pragma unroll
    for (int e4 = 0; e4 < 16; ++e4) {      // compile-time trip: loads batched
        int e = tid + 256 * e4;
        int q = idx[e];
        atomicAdd(&c_l[q], 1);
        if (mv) {
            float r = yt[e] - yp[e];
            atomicAdd(&s_l[q], r);
            rr_acc += r * r;
        }
    }
    __syncthreads();
    for (int j = tid; j < 1024; j += 256) sq_l[j] = sqrtf((float)c_l[j]);
    __syncthreads();

    if (bid == 0) {
        // build 64x64 diag tile in LDS, factor, write cols 0..63 only
        for (int kk = tid; kk < 4096; kk += 256) {
            int i = kk >> 6, j = kk & 63;
            float qi = sq_l[i] * inv_se * sb0;
            Pc[i * 65 + j] = ((i == j) ? 1.0f : 0.0f)
                           + qi * sq_l[j] * __expf(-dist[(size_t)i * QQ + j] * inv2);
        }
        __syncthreads();
        int i = lane, q = wid;
        float x[16];
#pragma unroll
        for (int m = 0; m < 16; ++m) x[m] = Pc[i * 65 + 16 * q + m];
        potrf64_run(x, i, q, col2);
        float* row = A + (size_t)i * LDA + 16 * q;
#pragma unroll
        for (int m4 = 0; m4 < 4; ++m4)
            ((float4*)row)[m4] = make_float4(x[4 * m4], x[4 * m4 + 1],
                                             x[4 * m4 + 2], x[4 * m4 + 3]);
        if (tid == 0) scal[2] = 0.f;    // w-chunk sq accumulator (panels add)
    } else if (!mv) {
        // blocks 1..127: rows 64..1023, one float4/thread/row
        for (int i = 64 + (bid - 1); i < QQ; i += 127) {
            float qi = sq_l[i] * inv_se * sb0;
            float4 d = ((const float4*)(dist + (size_t)i * QQ))[tid];
            int j0 = 4 * tid;
            float4 o;
            o.x = ((i == j0    ) ? 1.0f : 0.0f) + qi * sq_l[j0    ] * __expf(-d.x * inv2);
            o.y = ((i == j0 + 1) ? 1.0f : 0.0f) + qi * sq_l[j0 + 1] * __expf(-d.y * inv2);
            o.z = ((i == j0 + 2) ? 1.0f : 0.0f) + qi * sq_l[j0 + 2] * __expf(-d.z * inv2);
            o.w = ((i == j0 + 3) ? 1.0f : 0.0f) + qi * sq_l[j0 + 3] * __expf(-d.w * inv2);
            ((float4*)(A + (size_t)i * LDA))[tid] = o;
        }
    } else {
        int m = bid - 128;
        if (bid == 128) {   // rr reduce -> scal[0]
            float v = rr_acc;
            for (int o = 32; o > 0; o >>= 1) v += __shfl_down(v, o, 64);
            if (lane == 0) red[wid] = v;
            __syncthreads();
            if (tid == 0) scal[0] = red[0] + red[1] + red[2] + red[3];
            __syncthreads();
        }
        // 8 matvec rows: 2 per wave; inner dot fully unrolled (16 loads in flight)
        float st_acc = 0.f;
#pragma unroll
        for (int h = 0; h < 2; ++h) {
            int row = m * 8 + wid * 2 + h;
            const float* dr = dist + (size_t)row * QQ;
            float acc = 0.f;
#pragma unroll
            for (int j4 = 0; j4 < 16; ++j4) {
                int j = lane + 64 * j4;
                acc += __expf(-dr[j] * inv2) * s_l[j];
            }
            for (int o = 32; o > 0; o >>= 1) acc += __shfl_down(acc, o, 64);
            if (lane == 0) {
                float tv = acc * sb0;
                A[(size_t)QQ * LDA + row] = sq_l[row] * tv;   // w-row
                st_acc += s_l[row] * tv;
            }
        }
        __syncthreads();
        if (lane == 0) red[wid] = st_acc;
        __syncthreads();
        if (tid == 0) scal[16 + m] = red[0] + red[1] + red[2] + red[3];
    }
}

// ======== k_panel: one tile per block (p = 0..14) ========
__global__ __launch_bounds__(256) void k_panel(float* __restrict__ A,
                                               float* __restrict__ scal, int p) {
    __shared__ __align__(16) float PrRaw[64 * 68];
    __shared__ __align__(16) float PcRaw[64 * 68];
    __shared__ float2 col2[2][64];
    __shared__ float Lb[64][65];
    __shared__ float dinv[64];
    int t0v = (p + 1) * 64;
    int rows = (QQ + 1) - t0v;
    int nr = (rows + 63) >> 6;
    int ncol = (QQ - t0v) / 64;
    int by = -1, bx = 0, rem = blockIdx.x;
    for (int b = 0; b < nr; ++b) {
        int cn = (b + 1 < ncol) ? (b + 1) : ncol;
        if (cn < 1) cn = 1;                // p=14: ncol=0, but w-row tile exists
        if (rem < cn) { by = b; bx = rem; break; }
        rem -= cn;
    }
    if (by < 0) return;
    panel_tile(A, scal, p, by, bx, nr, ncol, PrRaw, PcRaw, col2, Lb, dinv);
}

// ======== k_final: solve chunk 15 vs factored diag15, reduce, combine ========
__global__ __launch_bounds__(256) void k_final(float* __restrict__ A,
                                               float* __restrict__ scal,
                                               const float* __restrict__ se_p,
                                               float* __restrict__ out) {
    const int tid = threadIdx.x;
    const int lane = tid & 63, wid = tid >> 6;
    __shared__ float Lb[64][65];
    __shared__ float r1s[4], r2s[4], r3s[4];
    __shared__ float wl[64];
    const float* db15 = A + (size_t)960 * LDA + 960;
    for (int kk = tid; kk < 4096; kk += 256) {
        int ii = kk >> 6, jj = kk & 63;
        Lb[ii][jj] = db15[(size_t)ii * LDA + jj];
    }
    __syncthreads();
    if (tid < 64) {
        float xv = A[(size_t)QQ * LDA + 960 + tid];
        for (int k = 0; k < 64; ++k) {
            if (tid == k) xv /= Lb[k][k];
            float xk = __shfl(xv, k, 64);
            if (tid > k) xv = fmaf(-Lb[tid][k], xk, xv);
        }
        wl[tid] = xv;
    }
    __syncthreads();
    float v1 = 0.f, v2 = 0.f;
    for (int i = tid; i < QQ; i += 256) {
        v1 += __logf(A[(size_t)i * LDA + i]);
        if (i >= 960) { float yv = wl[i - 960]; v2 += yv * yv; }
    }
    v1 *= 2.0f;
    float v3 = (tid < 128) ? scal[16 + tid] : 0.f;   // st partials
    for (int o = 32; o > 0; o >>= 1) {
        v1 += __shfl_down(v1, o, 64);
        v2 += __shfl_down(v2, o, 64);
        v3 += __shfl_down(v3, o, 64);
    }
    if (lane == 0) { r1s[wid] = v1; r2s[wid] = v2; r3s[wid] = v3; }
    __syncthreads();
    if (tid == 0) {
        float ld = r1s[0] + r1s[1] + r1s[2] + r1s[3];
        float wsq = __hip_atomic_load(&scal[2], __ATOMIC_RELAXED, __HIP_MEMORY_SCOPE_AGENT);
        float yy = r2s[0] + r2s[1] + r2s[2] + r2s[3] + wsq;  // chunks 0..14 + 15
        float st = r3s[0] + r3s[1] + r3s[2] + r3s[3];
        float se = se_p[0], inv = 1.0f / se;
        float rr = scal[0];
        float quad = rr * inv - inv * inv * (st - inv * yy);
        float logdetV = (float)NN * __logf(se) + ld;
        out[0] = 0.5f * (float)NN * 1.8378770664093453f + 0.5f * logdetV + 0.5f * quad;
    }
}

extern "C" void kernel_launch(void* const* d_in, const int* in_sizes, int n_in,
                              void* d_out, int out_size, void* d_ws, size_t ws_size,
                              hipStream_t stream) {
    const float* yt   = (const float*)d_in[0];
    const float* yp   = (const float*)d_in[1];
    const int*   idx  = (const int*)d_in[2];
    const float* dist = (const float*)d_in[3];
    const float* se   = (const float*)d_in[4];
    const float* sbs  = (const float*)d_in[5];
    float* out = (float*)d_out;

    float* W    = (float*)d_ws;
    float* A    = W;                      // 1025 x LDA
    float* scal = W + AF;                 // [0]=rr, [2]=wsq, [16..143]=st partials

    k_front<<<dim3(256), dim3(256), 0, stream>>>(yt, yp, idx, dist, se, sbs, A, scal);
    for (int p = 0; p <= 14; ++p) {
        int t0v = (p + 1) * 64;
        int nr = ((QQ + 1) - t0v + 63) / 64;
        int ncol = (QQ - t0v) / 64;
        int tiles = 0;
        for (int b = 0; b < nr; ++b) {
            int cn = (b + 1 < ncol) ? (b + 1) : ncol;
            if (cn < 1) cn = 1;           // p=14: w-row tile at ncol=0
            tiles += cn;
        }
        k_panel<<<dim3(tiles), dim3(256), 0, stream>>>(A, scal, p);
    }
    k_final<<<dim3(1), dim3(256), 0, stream>>>(A, scal, se, out);
}